// Round 10
// baseline (224.839 us; speedup 1.0000x reference)
//
#include <hip/hip_runtime.h>
#include <stdint.h>

// Hard voxelization, MI355X. f32x4 points -> f32 concat out:
//   voxels[60000,32,4], coors[60000,3](z,y,x), npv[60000], voxel_num[1].
//
// R9 forensics: reads are Infinity-Cache-absorbed (k_build FETCH 9.4MB < input);
// only scattered atomic WRITE lines reach HBM (57MB = 895K atomics x 64B ==
// measured). k_build ~45us is the algorithmic floor. R10 targets the rest:
//  - k_emit: thread-per-row -> coalesced 30.7MB store (was 512B/thread).
//  - 5 launches: scan folded into partials (last-block ticket, nb=235<=256);
//    scatter folded into assign (dupcnt decouples write order).
//  - pslot deleted: CANDBIT lives in pflat; dups re-probe read-only h64 (L3).

#define GX 1024
#define GY 1024
#define GZ 40
#define MAXV 60000
#define MAXP 32
#define HBITS 21
#define HSIZE (1u << HBITS)
#define HMASK (HSIZE - 1u)
#define CANDBIT (1 << 30)
#define FLATMASK (CANDBIT - 1)
#define TB 256
#define ITEMS 20
#define TILE (TB * ITEMS)   // 5120
#define WPB (TILE / 64)     // 80 flag words per block
#define EMPTY64 0xFFFFFFFFFFFFFFFFull

#define OFF_COORS ((size_t)MAXV * MAXP * 4)            // 7,680,000
#define OFF_NPV   (OFF_COORS + (size_t)MAXV * 3)       // 7,860,000
#define OFF_VNUM  (OFF_NPV + (size_t)MAXV)             // 7,920,000

typedef unsigned long long u64;

__device__ __forceinline__ unsigned hashf(int flat) {
    return ((unsigned)flat * 2654435761u) >> (32 - HBITS);
}

// ---- init: h64=EMPTY, dupcnt=0, repidx=-1, done=0, contested=0, coors=0 ----
__global__ void k_init(u64* __restrict__ h64, int* __restrict__ dupcnt,
                       int* __restrict__ repidx, int* __restrict__ done,
                       unsigned char* __restrict__ contested, int n,
                       float* __restrict__ oF) {
    int i = blockIdx.x * blockDim.x + threadIdx.x;
    int stride = gridDim.x * blockDim.x;
    for (int j = i; j < (int)HSIZE; j += stride) h64[j] = EMPTY64;
    for (int j = i; j < MAXV; j += stride) { dupcnt[j] = 0; repidx[j] = -1; }
    int nw = (n + 3) / 4;
    unsigned* c4 = (unsigned*)contested;
    for (int j = i; j < nw; j += stride) c4[j] = 0;
    for (int j = i; j < MAXV * 3; j += stride) oF[OFF_COORS + j] = 0.f;
    if (i == 0) *done = 0;
}

__device__ __forceinline__ int voxel_flat(float4 pt) {
    // identical IEEE f32 math to reference
    float fx = floorf((pt.x + 51.2f) / 0.1f);
    float fy = floorf((pt.y + 51.2f) / 0.1f);
    float fz = floorf((pt.z + 5.0f) / 0.2f);
    int cx = (int)fx, cy = (int)fy, cz = (int)fz;
    bool valid = (fx >= 0.f) & (cx < GX) & (fy >= 0.f) & (cy < GY) & (fz >= 0.f) & (cz < GZ);
    return valid ? (cx * GY + cy) * GZ + cz : -1;
}

// ---- build: 1 CAS typ.; pflat = flat | CANDBIT(candidate), -1 invalid ----
__global__ __launch_bounds__(TB) void k_build(const float4* __restrict__ pts, int n,
                                              u64* __restrict__ h64,
                                              int* __restrict__ pflat,
                                              unsigned char* __restrict__ contested) {
    int p = blockIdx.x * blockDim.x + threadIdx.x;
    if (p >= n) return;
    float4 pt = pts[p];
    int flat = voxel_flat(pt);
    if (flat < 0) { pflat[p] = -1; return; }
    u64 want = ((u64)(unsigned)flat << 32) | (unsigned)p;
    unsigned slot = hashf(flat);
    int cand = 0;
    for (int probe = 0; probe < 4096; probe++) {          // bounded: hang-proof
        u64 cur = atomicCAS(&h64[slot], EMPTY64, want);
        if (cur == EMPTY64) { cand = 1; break; }          // insert winner
        if ((unsigned)(cur >> 32) == (unsigned)flat) {    // existing voxel
            if ((unsigned)cur > (unsigned)p) {
                u64 old = atomicMin(&h64[slot], want);    // key equal -> compares rep
                unsigned oldrep = (unsigned)old;
                if (oldrep > (unsigned)p) {               // we really lowered it
                    contested[oldrep] = 1;                // previous holder dethroned
                    cand = 1;
                }
            }
            break;
        }
        slot = (slot + 1u) & HMASK;
    }
    pflat[p] = flat | (cand ? CANDBIT : 0);
}

// ---- partials: flag = cand && !contested -> flagbits + block sums;
//      last-finishing block converts sums to exclusive offsets + voxel_num ----
__global__ __launch_bounds__(TB) void k_partials(const int* __restrict__ pflat,
                                                 const unsigned char* __restrict__ contested,
                                                 int n, u64* __restrict__ flagbits,
                                                 int* __restrict__ partials,
                                                 int* __restrict__ done, int nb,
                                                 float* __restrict__ oF) {
    __shared__ int sh[TB];
    __shared__ int ticket;
    int t = threadIdx.x;
    int blk = blockIdx.x;
    int base = blk * TILE;
    int s = 0;
    #pragma unroll
    for (int j = 0; j < ITEMS; j++) {
        int i = base + j * TB + t;
        int pred = 0;
        if (i < n) {
            int pf = pflat[i];
            pred = (pf >= 0) && (pf & CANDBIT) && !contested[i];
        }
        u64 m = __ballot(pred);
        if ((t & 63) == 0) flagbits[i >> 6] = m;   // i 64-aligned at lane 0
        s += pred;
    }
    sh[t] = s;
    __syncthreads();
    for (int off = TB / 2; off > 0; off >>= 1) {
        if (t < off) sh[t] += sh[t + off];
        __syncthreads();
    }
    if (t == 0) partials[blk] = sh[0];
    __threadfence();                                // partials[blk] visible first
    if (t == 0) ticket = atomicAdd(done, 1);
    __syncthreads();
    if (ticket == nb - 1) {                         // we finished last: do the scan
        __threadfence();
        int v = (t < nb) ? partials[t] : 0;         // nb <= 256 (n <= 1.31M)
        sh[t] = v;
        __syncthreads();
        for (int off = 1; off < TB; off <<= 1) {
            int add = (t >= off) ? sh[t - off] : 0;
            __syncthreads();
            sh[t] += add;
            __syncthreads();
        }
        if (t < nb) partials[t] = sh[t] - v;        // exclusive offsets
        if (t == TB - 1) {
            int total = sh[TB - 1];
            if (total > MAXV) total = MAXV;
            oF[OFF_VNUM] = (float)total;            // voxel_num
        }
    }
}

// ---- finish: assign vids (coors, repidx) + dup scatter (dupcnt, list) ----
__global__ __launch_bounds__(TB) void k_finish(const u64* __restrict__ flagbits,
                                               const int* __restrict__ partials,
                                               const int* __restrict__ pflat,
                                               const u64* __restrict__ h64,
                                               int* __restrict__ repidx,
                                               int* __restrict__ dupcnt,
                                               int* __restrict__ list, int n,
                                               float* __restrict__ oF) {
    __shared__ int sh[TB];
    int t = threadIdx.x;
    int blk = blockIdx.x;
    int base = blk * TILE;
    int bitpos = t * ITEMS;                          // local bit 0..5100
    int gw = blk * WPB + (bitpos >> 6);
    int shmt = bitpos & 63;
    u64 win = flagbits[gw] >> shmt;
    if (shmt) win |= flagbits[gw + 1] << (64 - shmt);   // +1 word padded
    unsigned bits = (unsigned)(win & ((1u << ITEMS) - 1));
    int s = __popc(bits);
    sh[t] = s;
    __syncthreads();
    for (int off = 1; off < TB; off <<= 1) {
        int add = (t >= off) ? sh[t - off] : 0;
        __syncthreads();
        sh[t] += add;
        __syncthreads();
    }
    int vid = partials[blk] + (sh[t] - s);
    int i0 = base + bitpos;
    for (int j = 0; j < ITEMS; j++) {
        int i = i0 + j;
        if (i >= n) break;
        int pf = pflat[i];
        if ((bits >> j) & 1) {                       // first occurrence (rep)
            if (vid < MAXV) {
                int flat = pf & FLATMASK;
                int zc = flat % GZ;
                int t2 = flat / GZ;
                int yc = t2 % GY;
                int xc = t2 / GY;
                size_t cOff = OFF_COORS + (size_t)vid * 3;
                oF[cOff + 0] = (float)zc;
                oF[cOff + 1] = (float)yc;
                oF[cOff + 2] = (float)xc;
                repidx[vid] = i;
            }
            vid++;
        } else if (pf >= 0) {                        // dup (~9.4K total)
            int flat = pf & FLATMASK;
            unsigned slot = hashf(flat);
            unsigned rep = 0xFFFFFFFFu;
            for (int probe = 0; probe < 4096; probe++) {   // read-only re-probe
                u64 cur = h64[slot];
                if ((unsigned)(cur >> 32) == (unsigned)flat) { rep = (unsigned)cur; break; }
                if (cur == EMPTY64) break;
                slot = (slot + 1u) & HMASK;
            }
            if (rep != 0xFFFFFFFFu) {
                int br = (int)(rep / TILE);
                int lb = (int)(rep - (unsigned)br * TILE);
                int dvid = partials[br];
                int wb = br * WPB;
                int nw = lb >> 6;
                for (int w = 0; w < nw; w++) dvid += __popcll(flagbits[wb + w]);
                int tail = lb & 63;
                if (tail) dvid += __popcll(flagbits[wb + nw] & ((1ull << tail) - 1ull));
                if (dvid < MAXV) {
                    int pos = atomicAdd(&dupcnt[dvid], 1);
                    if (pos < MAXP - 1) list[dvid * (MAXP - 1) + pos] = i;
                }
            }
        }
    }
}

// ---- emit: thread-per-row, fully coalesced voxels store; npv ----
__global__ __launch_bounds__(TB) void k_emit(const float4* __restrict__ pts,
                                             const int* __restrict__ repidx,
                                             const int* __restrict__ dupcnt,
                                             const int* __restrict__ list,
                                             float4* __restrict__ outVox,
                                             float* __restrict__ oF) {
    int gid = blockIdx.x * TB + threadIdx.x;
    int vid = gid >> 5;                              // 8 voxels per block
    if (vid >= MAXV) return;
    int r = gid & 31;
    int ri = repidx[vid];
    int dc = dupcnt[vid];
    int d = dc < (MAXP - 1) ? dc : (MAXP - 1);
    int m = (ri >= 0) ? (1 + d) : 0;
    if (r == 0) oF[OFF_NPV + vid] = (float)m;
    float4 row = make_float4(0.f, 0.f, 0.f, 0.f);
    if (r == 0 && m > 0) {
        row = pts[ri];                               // rep = provably min index
    } else if (r < m) {                              // dup rows, ascending index
        const int* lst = &list[vid * (MAXP - 1)];
        int target = r - 1, pick = -1;
        for (int a = 0; a < d; a++) {
            int e = lst[a];
            int rk = 0;
            for (int b = 0; b < d; b++) rk += (lst[b] < e);
            if (rk == target) pick = e;
        }
        row = pts[pick];
    }
    outVox[(size_t)vid * MAXP + r] = row;            // coalesced 16B x 64 lanes
}

extern "C" void kernel_launch(void* const* d_in, const int* in_sizes, int n_in,
                              void* d_out, int out_size, void* d_ws, size_t ws_size,
                              hipStream_t stream) {
    int n = in_sizes[0] / 4;                       // 1,200,000
    const float4* pts = (const float4*)d_in[0];

    int tb = TB;
    int nbp = (n + tb - 1) / tb;
    int nb = (n + TILE - 1) / TILE;                // 235 (must be <= 256)
    int nwords = nb * WPB + 1;                     // +1 pad for window reads

    // ws layout, ~31 MB
    char* base = (char*)d_ws;
    size_t o = 0;
    int* partials = (int*)(base + o);  o += 1024;
    int* done     = (int*)(base + o);  o += 256;
    int* dupcnt   = (int*)(base + o);  o += (size_t)MAXV * 4;
    int* repidx   = (int*)(base + o);  o += (size_t)MAXV * 4;
    o = (o + 255) & ~(size_t)255;
    u64* flagbits = (u64*)(base + o);  o += (size_t)nwords * 8;
    o = (o + 255) & ~(size_t)255;
    unsigned char* contested = (unsigned char*)(base + o);  o += ((size_t)n + 255) & ~(size_t)255;
    u64* h64      = (u64*)(base + o);  o += (size_t)HSIZE * 8;
    int* pflat    = (int*)(base + o);  o += (size_t)n * 4;
    int* list     = (int*)(base + o);  o += (size_t)MAXV * (MAXP - 1) * 4;

    float* oF = (float*)d_out;

    k_init<<<2048, tb, 0, stream>>>(h64, dupcnt, repidx, done, contested, n, oF);
    k_build<<<nbp, tb, 0, stream>>>(pts, n, h64, pflat, contested);
    k_partials<<<nb, tb, 0, stream>>>(pflat, contested, n, flagbits, partials, done, nb, oF);
    k_finish<<<nb, tb, 0, stream>>>(flagbits, partials, pflat, h64, repidx, dupcnt, list, n, oF);
    k_emit<<<(MAXV * MAXP + tb - 1) / tb, tb, 0, stream>>>(pts, repidx, dupcnt, list,
                                                           (float4*)d_out, oF);
}

// Round 11
// 199.673 us; speedup vs baseline: 1.1260x; 1.1260x over previous
//
#include <hip/hip_runtime.h>
#include <stdint.h>

// Hard voxelization, MI355X. f32x4 points -> f32 concat out:
//   voxels[60000,32,4], coors[60000,3](z,y,x), npv[60000], voxel_num[1].
//
// R10 forensics: mid-pipeline kernels were GRID-STARVED SERIAL LOOPS (k_finish
// 72us @ 4% occupancy, ~zero traffic, ~zero VALU — pure unhidden latency from
// 235 blocks x 20-deep dependent loops). R11: 1 point/thread everywhere
// (4688-block grids), ballot+popcount ranks, no ITEMS loops. k_build stays at
// its scattered-atomic write-through ceiling (~46us, ILP-proof per R7).

#define GX 1024
#define GY 1024
#define GZ 40
#define MAXV 60000
#define MAXP 32
#define HBITS 20
#define HSIZE (1u << HBITS)
#define HMASK (HSIZE - 1u)
#define CANDBIT (1 << 30)
#define FLATMASK (CANDBIT - 1)
#define TB 256
#define EMPTY64 0xFFFFFFFFFFFFFFFFull

#define OFF_COORS ((size_t)MAXV * MAXP * 4)            // 7,680,000
#define OFF_NPV   (OFF_COORS + (size_t)MAXV * 3)       // 7,860,000
#define OFF_VNUM  (OFF_NPV + (size_t)MAXV)             // 7,920,000

typedef unsigned long long u64;

__device__ __forceinline__ unsigned hashf(int flat) {
    return ((unsigned)flat * 2654435761u) >> (32 - HBITS);
}

// ---- init: h64=EMPTY(8MB), contested=0, dupcnt=0, repidx=-1, coors=0 ----
__global__ void k_init(u64* __restrict__ h64, unsigned char* __restrict__ contested,
                       int* __restrict__ dupcnt, int* __restrict__ repidx,
                       int n, float* __restrict__ oF) {
    int i = blockIdx.x * blockDim.x + threadIdx.x;
    int stride = gridDim.x * blockDim.x;
    for (int j = i; j < (int)HSIZE; j += stride) h64[j] = EMPTY64;
    int nw = (n + 3) / 4;
    unsigned* c4 = (unsigned*)contested;
    for (int j = i; j < nw; j += stride) c4[j] = 0;
    for (int j = i; j < MAXV; j += stride) { dupcnt[j] = 0; repidx[j] = -1; }
    for (int j = i; j < MAXV * 3; j += stride) oF[OFF_COORS + j] = 0.f;
}

__device__ __forceinline__ int voxel_flat(float4 pt) {
    // identical IEEE f32 math to reference
    float fx = floorf((pt.x + 51.2f) / 0.1f);
    float fy = floorf((pt.y + 51.2f) / 0.1f);
    float fz = floorf((pt.z + 5.0f) / 0.2f);
    int cx = (int)fx, cy = (int)fy, cz = (int)fz;
    bool valid = (fx >= 0.f) & (cx < GX) & (fy >= 0.f) & (cy < GY) & (fz >= 0.f) & (cz < GZ);
    return valid ? (cx * GY + cy) * GZ + cz : -1;
}

// ---- build: 1 CAS typ.; pflat = flat | CANDBIT(candidate), -1 invalid ----
__global__ __launch_bounds__(TB) void k_build(const float4* __restrict__ pts, int n,
                                              u64* __restrict__ h64,
                                              int* __restrict__ pflat,
                                              unsigned char* __restrict__ contested) {
    int p = blockIdx.x * blockDim.x + threadIdx.x;
    if (p >= n) return;
    float4 pt = pts[p];
    int flat = voxel_flat(pt);
    if (flat < 0) { pflat[p] = -1; return; }
    u64 want = ((u64)(unsigned)flat << 32) | (unsigned)p;
    unsigned slot = hashf(flat);
    int cand = 0;
    for (int probe = 0; probe < 4096; probe++) {          // bounded: hang-proof
        u64 cur = atomicCAS(&h64[slot], EMPTY64, want);
        if (cur == EMPTY64) { cand = 1; break; }          // insert winner
        if ((unsigned)(cur >> 32) == (unsigned)flat) {    // existing voxel
            if ((unsigned)cur > (unsigned)p) {
                u64 old = atomicMin(&h64[slot], want);    // key equal -> compares rep
                unsigned oldrep = (unsigned)old;
                if (oldrep > (unsigned)p) {               // we really lowered it
                    contested[oldrep] = 1;                // previous holder dethroned
                    cand = 1;
                }
            }
            break;
        }
        slot = (slot + 1u) & HMASK;
    }
    pflat[p] = flat | (cand ? CANDBIT : 0);
}

// ---- flags: 1 pt/thread; ballot -> flag word + block sum. No loops. ----
__global__ __launch_bounds__(TB) void k_flags(const int* __restrict__ pflat,
                                              const unsigned char* __restrict__ contested,
                                              int n, u64* __restrict__ flagbits,
                                              int* __restrict__ partials) {
    __shared__ int ws[4];
    int b = blockIdx.x, t = threadIdx.x;
    int i = b * TB + t;
    int pred = 0;
    if (i < n) {
        int pf = pflat[i];
        pred = (pf >= 0) && (pf & CANDBIT) && !contested[i];
    }
    u64 m = __ballot(pred);
    int w = t >> 6, lane = t & 63;
    if (lane == 0) { flagbits[b * 4 + w] = m; ws[w] = __popcll(m); }
    __syncthreads();
    if (t == 0) partials[b] = ws[0] + ws[1] + ws[2] + ws[3];
}

// ---- scan: one 1024-thread block, 5 partials/thread -> exclusive offsets ----
__global__ __launch_bounds__(1024) void k_scan(int* __restrict__ partials, int npart,
                                               float* __restrict__ oF) {
    __shared__ int sh[1024];
    int t = threadIdx.x;
    int v[5];
    int s = 0;
    #pragma unroll
    for (int k = 0; k < 5; k++) {
        int idx = t * 5 + k;
        v[k] = (idx < npart) ? partials[idx] : 0;
        s += v[k];
    }
    sh[t] = s;
    __syncthreads();
    for (int off = 1; off < 1024; off <<= 1) {
        int add = (t >= off) ? sh[t - off] : 0;
        __syncthreads();
        sh[t] += add;
        __syncthreads();
    }
    int run = sh[t] - s;                     // exclusive base for this thread
    #pragma unroll
    for (int k = 0; k < 5; k++) {
        int idx = t * 5 + k;
        if (idx < npart) partials[idx] = run;
        run += v[k];
    }
    if (t == 1023) {
        int total = sh[1023];
        if (total > MAXV) total = MAXV;
        oF[OFF_VNUM] = (float)total;         // voxel_num
    }
}

// ---- finish: 1 pt/thread; vid via popcount rank; reps->coors/repidx,
//      dups(~9K)->h64 re-probe + rank -> dupcnt/list ----
__global__ __launch_bounds__(TB) void k_finish(const u64* __restrict__ flagbits,
                                               const int* __restrict__ partials,
                                               const int* __restrict__ pflat,
                                               const u64* __restrict__ h64,
                                               int* __restrict__ repidx,
                                               int* __restrict__ dupcnt,
                                               int* __restrict__ list, int n,
                                               float* __restrict__ oF) {
    int b = blockIdx.x, t = threadIdx.x;
    int i = b * TB + t;
    if (i >= n) return;
    int lane = t & 63, w = t >> 6;
    u64 w0 = flagbits[b * 4 + 0];
    u64 w1 = flagbits[b * 4 + 1];
    u64 w2 = flagbits[b * 4 + 2];
    u64 w3 = flagbits[b * 4 + 3];
    u64 myw = (w == 0) ? w0 : (w == 1) ? w1 : (w == 2) ? w2 : w3;
    int bit = (int)((myw >> lane) & 1);
    int pf = pflat[i];
    if (bit) {                                           // first occurrence (rep)
        int wbase = (w > 0 ? __popcll(w0) : 0) + (w > 1 ? __popcll(w1) : 0)
                  + (w > 2 ? __popcll(w2) : 0);
        int vid = partials[b] + wbase + (int)__popcll(myw & ((1ull << lane) - 1ull));
        if (vid < MAXV) {
            int flat = pf & FLATMASK;
            int zc = flat % GZ;
            int t2 = flat / GZ;
            int yc = t2 % GY;
            int xc = t2 / GY;
            size_t cOff = OFF_COORS + (size_t)vid * 3;
            oF[cOff + 0] = (float)zc;
            oF[cOff + 1] = (float)yc;
            oF[cOff + 2] = (float)xc;
            repidx[vid] = i;
        }
    } else if (pf >= 0) {                                // non-rep valid (~9K)
        int flat = pf & FLATMASK;
        unsigned slot = hashf(flat);
        unsigned rep = 0xFFFFFFFFu;
        for (int probe = 0; probe < 4096; probe++) {     // read-only, L3-hot
            u64 cur = h64[slot];
            if ((unsigned)(cur >> 32) == (unsigned)flat) { rep = (unsigned)cur; break; }
            if (cur == EMPTY64) break;
            slot = (slot + 1u) & HMASK;
        }
        if (rep != 0xFFFFFFFFu) {
            int br = (int)(rep >> 8);                    // rep's 256-block
            int lb = (int)(rep & 255u);
            int dvid = partials[br];
            int wb = br * 4, nw = lb >> 6;
            for (int q = 0; q < nw; q++) dvid += (int)__popcll(flagbits[wb + q]);
            int tail = lb & 63;
            if (tail) dvid += (int)__popcll(flagbits[wb + nw] & ((1ull << tail) - 1ull));
            if (dvid < MAXV) {
                int pos = atomicAdd(&dupcnt[dvid], 1);
                if (pos < MAXP - 1) list[dvid * (MAXP - 1) + pos] = i;
            }
        }
    }
}

// ---- emit: thread-per-row, fully coalesced voxels store; npv ----
__global__ __launch_bounds__(TB) void k_emit(const float4* __restrict__ pts,
                                             const int* __restrict__ repidx,
                                             const int* __restrict__ dupcnt,
                                             const int* __restrict__ list,
                                             float4* __restrict__ outVox,
                                             float* __restrict__ oF) {
    int gid = blockIdx.x * TB + threadIdx.x;
    int vid = gid >> 5;
    if (vid >= MAXV) return;
    int r = gid & 31;
    int ri = repidx[vid];
    int dc = dupcnt[vid];
    int d = dc < (MAXP - 1) ? dc : (MAXP - 1);
    int m = (ri >= 0) ? (1 + d) : 0;
    if (r == 0) oF[OFF_NPV + vid] = (float)m;
    float4 row = make_float4(0.f, 0.f, 0.f, 0.f);
    if (r == 0 && m > 0) {
        row = pts[ri];                               // rep = provably min index
    } else if (r < m) {                              // dup rows, ascending index
        const int* lst = &list[vid * (MAXP - 1)];
        int target = r - 1, pick = -1;
        for (int a = 0; a < d; a++) {
            int e = lst[a];
            int rk = 0;
            for (int bq = 0; bq < d; bq++) rk += (lst[bq] < e);
            if (rk == target) pick = e;
        }
        row = pts[pick];
    }
    outVox[(size_t)vid * MAXP + r] = row;            // coalesced 16B x 64 lanes
}

extern "C" void kernel_launch(void* const* d_in, const int* in_sizes, int n_in,
                              void* d_out, int out_size, void* d_ws, size_t ws_size,
                              hipStream_t stream) {
    int n = in_sizes[0] / 4;                       // 1,200,000
    const float4* pts = (const float4*)d_in[0];

    int tb = TB;
    int nbp = (n + tb - 1) / tb;                   // 4688 (1 pt/thread grids)
    int nwords = nbp * 4;                          // flag words (4 per block)

    // ws layout, ~22 MB
    char* base = (char*)d_ws;
    size_t o = 0;
    int* partials = (int*)(base + o);  o += ((size_t)nbp * 4 + 255) & ~(size_t)255;
    int* dupcnt   = (int*)(base + o);  o += (size_t)MAXV * 4;
    int* repidx   = (int*)(base + o);  o += (size_t)MAXV * 4;
    o = (o + 255) & ~(size_t)255;
    u64* flagbits = (u64*)(base + o);  o += (size_t)nwords * 8;
    o = (o + 255) & ~(size_t)255;
    unsigned char* contested = (unsigned char*)(base + o);  o += ((size_t)n + 255) & ~(size_t)255;
    u64* h64      = (u64*)(base + o);  o += (size_t)HSIZE * 8;
    int* pflat    = (int*)(base + o);  o += (size_t)n * 4;
    int* list     = (int*)(base + o);  o += (size_t)MAXV * (MAXP - 1) * 4;

    float* oF = (float*)d_out;

    k_init<<<2048, tb, 0, stream>>>(h64, contested, dupcnt, repidx, n, oF);
    k_build<<<nbp, tb, 0, stream>>>(pts, n, h64, pflat, contested);
    k_flags<<<nbp, tb, 0, stream>>>(pflat, contested, n, flagbits, partials);
    k_scan<<<1, 1024, 0, stream>>>(partials, nbp, oF);
    k_finish<<<nbp, tb, 0, stream>>>(flagbits, partials, pflat, h64, repidx, dupcnt, list, n, oF);
    k_emit<<<(MAXV * MAXP + tb - 1) / tb, tb, 0, stream>>>(pts, repidx, dupcnt, list,
                                                           (float4*)d_out, oF);
}

// Round 12
// 138.464 us; speedup vs baseline: 1.6238x; 1.4421x over previous
//
#include <hip/hip_runtime.h>
#include <stdint.h>

// Hard voxelization, MI355X. f32x4 points -> f32 concat out:
//   voxels[60000,32,4], coors[60000,3](z,y,x), npv[60000], voxel_num[1].
//
// R11 forensics: 1-pt/thread restructure fixed the grid-starved mid-pipeline
// (no mid kernel in top-5), but HBITS 20 blew up k_build (alpha 0.84 ->
// probe-cluster CAS storm: WRITE 63->103MB, 46->115us). R12: HBITS back to 21
// (alpha 0.42). k_build's ~46us = one 64B-line atomic per voxel through the
// coherence point (~1.4TB/s scattered-line ceiling; ILP-proof per R7).

#define GX 1024
#define GY 1024
#define GZ 40
#define MAXV 60000
#define MAXP 32
#define HBITS 21
#define HSIZE (1u << HBITS)
#define HMASK (HSIZE - 1u)
#define CANDBIT (1 << 30)
#define FLATMASK (CANDBIT - 1)
#define TB 256
#define EMPTY64 0xFFFFFFFFFFFFFFFFull

#define OFF_COORS ((size_t)MAXV * MAXP * 4)            // 7,680,000
#define OFF_NPV   (OFF_COORS + (size_t)MAXV * 3)       // 7,860,000
#define OFF_VNUM  (OFF_NPV + (size_t)MAXV)             // 7,920,000

typedef unsigned long long u64;

__device__ __forceinline__ unsigned hashf(int flat) {
    return ((unsigned)flat * 2654435761u) >> (32 - HBITS);
}

// ---- init: h64=EMPTY(16MB), contested=0, dupcnt=0, repidx=-1, coors=0 ----
__global__ void k_init(u64* __restrict__ h64, unsigned char* __restrict__ contested,
                       int* __restrict__ dupcnt, int* __restrict__ repidx,
                       int n, float* __restrict__ oF) {
    int i = blockIdx.x * blockDim.x + threadIdx.x;
    int stride = gridDim.x * blockDim.x;
    for (int j = i; j < (int)HSIZE; j += stride) h64[j] = EMPTY64;
    int nw = (n + 3) / 4;
    unsigned* c4 = (unsigned*)contested;
    for (int j = i; j < nw; j += stride) c4[j] = 0;
    for (int j = i; j < MAXV; j += stride) { dupcnt[j] = 0; repidx[j] = -1; }
    for (int j = i; j < MAXV * 3; j += stride) oF[OFF_COORS + j] = 0.f;
}

__device__ __forceinline__ int voxel_flat(float4 pt) {
    // identical IEEE f32 math to reference
    float fx = floorf((pt.x + 51.2f) / 0.1f);
    float fy = floorf((pt.y + 51.2f) / 0.1f);
    float fz = floorf((pt.z + 5.0f) / 0.2f);
    int cx = (int)fx, cy = (int)fy, cz = (int)fz;
    bool valid = (fx >= 0.f) & (cx < GX) & (fy >= 0.f) & (cy < GY) & (fz >= 0.f) & (cz < GZ);
    return valid ? (cx * GY + cy) * GZ + cz : -1;
}

// ---- build: 1 CAS typ.; pflat = flat | CANDBIT(candidate), -1 invalid ----
__global__ __launch_bounds__(TB) void k_build(const float4* __restrict__ pts, int n,
                                              u64* __restrict__ h64,
                                              int* __restrict__ pflat,
                                              unsigned char* __restrict__ contested) {
    int p = blockIdx.x * blockDim.x + threadIdx.x;
    if (p >= n) return;
    float4 pt = pts[p];
    int flat = voxel_flat(pt);
    if (flat < 0) { pflat[p] = -1; return; }
    u64 want = ((u64)(unsigned)flat << 32) | (unsigned)p;
    unsigned slot = hashf(flat);
    int cand = 0;
    for (int probe = 0; probe < 4096; probe++) {          // bounded: hang-proof
        u64 cur = atomicCAS(&h64[slot], EMPTY64, want);
        if (cur == EMPTY64) { cand = 1; break; }          // insert winner
        if ((unsigned)(cur >> 32) == (unsigned)flat) {    // existing voxel
            if ((unsigned)cur > (unsigned)p) {
                u64 old = atomicMin(&h64[slot], want);    // key equal -> compares rep
                unsigned oldrep = (unsigned)old;
                if (oldrep > (unsigned)p) {               // we really lowered it
                    contested[oldrep] = 1;                // previous holder dethroned
                    cand = 1;
                }
            }
            break;
        }
        slot = (slot + 1u) & HMASK;
    }
    pflat[p] = flat | (cand ? CANDBIT : 0);
}

// ---- flags: 1 pt/thread; ballot -> flag word + block sum. No loops. ----
__global__ __launch_bounds__(TB) void k_flags(const int* __restrict__ pflat,
                                              const unsigned char* __restrict__ contested,
                                              int n, u64* __restrict__ flagbits,
                                              int* __restrict__ partials) {
    __shared__ int ws[4];
    int b = blockIdx.x, t = threadIdx.x;
    int i = b * TB + t;
    int pred = 0;
    if (i < n) {
        int pf = pflat[i];
        pred = (pf >= 0) && (pf & CANDBIT) && !contested[i];
    }
    u64 m = __ballot(pred);
    int w = t >> 6, lane = t & 63;
    if (lane == 0) { flagbits[b * 4 + w] = m; ws[w] = __popcll(m); }
    __syncthreads();
    if (t == 0) partials[b] = ws[0] + ws[1] + ws[2] + ws[3];
}

// ---- scan: one 1024-thread block, 5 partials/thread -> exclusive offsets ----
__global__ __launch_bounds__(1024) void k_scan(int* __restrict__ partials, int npart,
                                               float* __restrict__ oF) {
    __shared__ int sh[1024];
    int t = threadIdx.x;
    int v[5];
    int s = 0;
    #pragma unroll
    for (int k = 0; k < 5; k++) {
        int idx = t * 5 + k;
        v[k] = (idx < npart) ? partials[idx] : 0;
        s += v[k];
    }
    sh[t] = s;
    __syncthreads();
    for (int off = 1; off < 1024; off <<= 1) {
        int add = (t >= off) ? sh[t - off] : 0;
        __syncthreads();
        sh[t] += add;
        __syncthreads();
    }
    int run = sh[t] - s;                     // exclusive base for this thread
    #pragma unroll
    for (int k = 0; k < 5; k++) {
        int idx = t * 5 + k;
        if (idx < npart) partials[idx] = run;
        run += v[k];
    }
    if (t == 1023) {
        int total = sh[1023];
        if (total > MAXV) total = MAXV;
        oF[OFF_VNUM] = (float)total;         // voxel_num
    }
}

// ---- finish: 1 pt/thread; vid via popcount rank; reps->coors/repidx,
//      dups(~9K)->h64 re-probe + rank -> dupcnt/list ----
__global__ __launch_bounds__(TB) void k_finish(const u64* __restrict__ flagbits,
                                               const int* __restrict__ partials,
                                               const int* __restrict__ pflat,
                                               const u64* __restrict__ h64,
                                               int* __restrict__ repidx,
                                               int* __restrict__ dupcnt,
                                               int* __restrict__ list, int n,
                                               float* __restrict__ oF) {
    int b = blockIdx.x, t = threadIdx.x;
    int i = b * TB + t;
    if (i >= n) return;
    int lane = t & 63, w = t >> 6;
    u64 w0 = flagbits[b * 4 + 0];
    u64 w1 = flagbits[b * 4 + 1];
    u64 w2 = flagbits[b * 4 + 2];
    u64 w3 = flagbits[b * 4 + 3];
    u64 myw = (w == 0) ? w0 : (w == 1) ? w1 : (w == 2) ? w2 : w3;
    int bit = (int)((myw >> lane) & 1);
    int pf = pflat[i];
    if (bit) {                                           // first occurrence (rep)
        int wbase = (w > 0 ? __popcll(w0) : 0) + (w > 1 ? __popcll(w1) : 0)
                  + (w > 2 ? __popcll(w2) : 0);
        int vid = partials[b] + wbase + (int)__popcll(myw & ((1ull << lane) - 1ull));
        if (vid < MAXV) {
            int flat = pf & FLATMASK;
            int zc = flat % GZ;
            int t2 = flat / GZ;
            int yc = t2 % GY;
            int xc = t2 / GY;
            size_t cOff = OFF_COORS + (size_t)vid * 3;
            oF[cOff + 0] = (float)zc;
            oF[cOff + 1] = (float)yc;
            oF[cOff + 2] = (float)xc;
            repidx[vid] = i;
        }
    } else if (pf >= 0) {                                // non-rep valid (~9K)
        int flat = pf & FLATMASK;
        unsigned slot = hashf(flat);
        unsigned rep = 0xFFFFFFFFu;
        for (int probe = 0; probe < 4096; probe++) {     // read-only, L3-hot
            u64 cur = h64[slot];
            if ((unsigned)(cur >> 32) == (unsigned)flat) { rep = (unsigned)cur; break; }
            if (cur == EMPTY64) break;
            slot = (slot + 1u) & HMASK;
        }
        if (rep != 0xFFFFFFFFu) {
            int br = (int)(rep >> 8);                    // rep's 256-block
            int lb = (int)(rep & 255u);
            int dvid = partials[br];
            int wb = br * 4, nw = lb >> 6;
            for (int q = 0; q < nw; q++) dvid += (int)__popcll(flagbits[wb + q]);
            int tail = lb & 63;
            if (tail) dvid += (int)__popcll(flagbits[wb + nw] & ((1ull << tail) - 1ull));
            if (dvid < MAXV) {
                int pos = atomicAdd(&dupcnt[dvid], 1);
                if (pos < MAXP - 1) list[dvid * (MAXP - 1) + pos] = i;
            }
        }
    }
}

// ---- emit: thread-per-row, fully coalesced voxels store; npv ----
__global__ __launch_bounds__(TB) void k_emit(const float4* __restrict__ pts,
                                             const int* __restrict__ repidx,
                                             const int* __restrict__ dupcnt,
                                             const int* __restrict__ list,
                                             float4* __restrict__ outVox,
                                             float* __restrict__ oF) {
    int gid = blockIdx.x * TB + threadIdx.x;
    int vid = gid >> 5;
    if (vid >= MAXV) return;
    int r = gid & 31;
    int ri = repidx[vid];
    int dc = dupcnt[vid];
    int d = dc < (MAXP - 1) ? dc : (MAXP - 1);
    int m = (ri >= 0) ? (1 + d) : 0;
    if (r == 0) oF[OFF_NPV + vid] = (float)m;
    float4 row = make_float4(0.f, 0.f, 0.f, 0.f);
    if (r == 0 && m > 0) {
        row = pts[ri];                               // rep = provably min index
    } else if (r < m) {                              // dup rows, ascending index
        const int* lst = &list[vid * (MAXP - 1)];
        int target = r - 1, pick = -1;
        for (int a = 0; a < d; a++) {
            int e = lst[a];
            int rk = 0;
            for (int bq = 0; bq < d; bq++) rk += (lst[bq] < e);
            if (rk == target) pick = e;
        }
        row = pts[pick];
    }
    outVox[(size_t)vid * MAXP + r] = row;            // coalesced 16B x 64 lanes
}

extern "C" void kernel_launch(void* const* d_in, const int* in_sizes, int n_in,
                              void* d_out, int out_size, void* d_ws, size_t ws_size,
                              hipStream_t stream) {
    int n = in_sizes[0] / 4;                       // 1,200,000
    const float4* pts = (const float4*)d_in[0];

    int tb = TB;
    int nbp = (n + tb - 1) / tb;                   // 4688 (1 pt/thread grids)
    int nwords = nbp * 4;                          // flag words (4 per block)

    // ws layout, ~30 MB
    char* base = (char*)d_ws;
    size_t o = 0;
    int* partials = (int*)(base + o);  o += ((size_t)nbp * 4 + 255) & ~(size_t)255;
    int* dupcnt   = (int*)(base + o);  o += (size_t)MAXV * 4;
    int* repidx   = (int*)(base + o);  o += (size_t)MAXV * 4;
    o = (o + 255) & ~(size_t)255;
    u64* flagbits = (u64*)(base + o);  o += (size_t)nwords * 8;
    o = (o + 255) & ~(size_t)255;
    unsigned char* contested = (unsigned char*)(base + o);  o += ((size_t)n + 255) & ~(size_t)255;
    u64* h64      = (u64*)(base + o);  o += (size_t)HSIZE * 8;
    int* pflat    = (int*)(base + o);  o += (size_t)n * 4;
    int* list     = (int*)(base + o);  o += (size_t)MAXV * (MAXP - 1) * 4;

    float* oF = (float*)d_out;

    k_init<<<2048, tb, 0, stream>>>(h64, contested, dupcnt, repidx, n, oF);
    k_build<<<nbp, tb, 0, stream>>>(pts, n, h64, pflat, contested);
    k_flags<<<nbp, tb, 0, stream>>>(pflat, contested, n, flagbits, partials);
    k_scan<<<1, 1024, 0, stream>>>(partials, nbp, oF);
    k_finish<<<nbp, tb, 0, stream>>>(flagbits, partials, pflat, h64, repidx, dupcnt, list, n, oF);
    k_emit<<<(MAXV * MAXP + tb - 1) / tb, tb, 0, stream>>>(pts, repidx, dupcnt, list,
                                                           (float4*)d_out, oF);
}